// Round 1
// baseline (6074.617 us; speedup 1.0000x reference)
//
#include <hip/hip_runtime.h>
#include <math.h>

// Problem constants (B=64, N=512, H=768), fp32 throughout.
static constexpr int B_ = 64;
static constexpr int N_ = 512;
static constexpr int H_ = 768;

// ---------------------------------------------------------------------------
// Kernel 1: xW = X @ W   (M x H) = (M x H) @ (H x H),  M = B*N = 32768
// Classic 64x64 tile, K-tile 16, 256 threads, 4x4 per-thread register tile.
// Output written into d_out (same size as xW); consumed as Q by kernel 2.
// ---------------------------------------------------------------------------
__global__ __launch_bounds__(256) void gemm_xw(const float* __restrict__ X,
                                               const float* __restrict__ W,
                                               float* __restrict__ C) {
    // As[k][m] (transposed A tile), Ws[k][n]; stride 68 floats = 272 B (16B-aligned rows, breaks bank pow2)
    __shared__ float As[16][68];
    __shared__ float Ws[16][68];

    const int t  = threadIdx.x;
    const int m0 = blockIdx.y * 64;
    const int n0 = blockIdx.x * 64;
    const int tx = t & 15, ty = t >> 4;
    const int tm = ty * 4, tn = tx * 4;

    // loader indices
    const int ar  = t >> 2;          // A tile row 0..63
    const int ac4 = (t & 3) * 4;     // A tile col (float4) 0/4/8/12
    const int wr  = t >> 4;          // W tile row 0..15
    const int wc4 = (t & 15) * 4;    // W tile col 0..60 step 4

    float acc[4][4] = {};

    for (int k0 = 0; k0 < H_; k0 += 16) {
        float4 av = *(const float4*)&X[(size_t)(m0 + ar) * H_ + k0 + ac4];
        float4 wv = *(const float4*)&W[(size_t)(k0 + wr) * H_ + n0 + wc4];
        __syncthreads();   // previous iteration's LDS reads complete
        As[ac4 + 0][ar] = av.x;
        As[ac4 + 1][ar] = av.y;
        As[ac4 + 2][ar] = av.z;
        As[ac4 + 3][ar] = av.w;
        *(float4*)&Ws[wr][wc4] = wv;
        __syncthreads();
        #pragma unroll
        for (int k = 0; k < 16; ++k) {
            float4 a4 = *(const float4*)&As[k][tm];
            float4 b4 = *(const float4*)&Ws[k][tn];
            acc[0][0] += a4.x * b4.x; acc[0][1] += a4.x * b4.y; acc[0][2] += a4.x * b4.z; acc[0][3] += a4.x * b4.w;
            acc[1][0] += a4.y * b4.x; acc[1][1] += a4.y * b4.y; acc[1][2] += a4.y * b4.z; acc[1][3] += a4.y * b4.w;
            acc[2][0] += a4.z * b4.x; acc[2][1] += a4.z * b4.y; acc[2][2] += a4.z * b4.z; acc[2][3] += a4.z * b4.w;
            acc[3][0] += a4.w * b4.x; acc[3][1] += a4.w * b4.y; acc[3][2] += a4.w * b4.z; acc[3][3] += a4.w * b4.w;
        }
    }

    #pragma unroll
    for (int r = 0; r < 4; ++r) {
        float4 v = make_float4(acc[r][0], acc[r][1], acc[r][2], acc[r][3]);
        *(float4*)&C[(size_t)(m0 + tm + r) * H_ + n0 + tn] = v;
    }
}

// ---------------------------------------------------------------------------
// Kernel 2: flash-style attention. Block = 256 threads = one (b, 16-row i-tile).
// Q (=xW rows, read from d_out) lives in registers: thread t owns row il=t>>4,
// h-subset {4*(t&15) + 64u, u=0..11}. X j-tiles (16 x 768 fp32) staged in LDS.
// Scores: per-thread partial dot + shfl_xor(width=16) reduce -> every lane of
// an il-group holds all 16 tile scores. Online softmax; PV accumulated in regs.
// Each block finally overwrites its own 16 rows of d_out. No workspace needed.
// ---------------------------------------------------------------------------
__global__ __launch_bounds__(256) void attn(const float* __restrict__ X,
                                            const float* __restrict__ bias_p,
                                            float* Out) {
    __shared__ float Xs[16 * H_];   // 49152 B

    const int t  = threadIdx.x;
    const int b  = blockIdx.y;
    const int i0 = blockIdx.x * 16;
    const int il = t >> 4;     // 0..15 local i row
    const int hq = t & 15;     // h-stripe id
    const int gi = i0 + il;
    const float bias = bias_p[0];

    const float* xb = X + (size_t)b * N_ * H_;
    float* orow = Out + ((size_t)b * N_ + gi) * H_;

    // Q fragment (xW row gi), 48 floats per thread
    float4 q[12];
    #pragma unroll
    for (int u = 0; u < 12; ++u)
        q[u] = *(const float4*)&orow[hq * 4 + 64 * u];

    float4 o[12];
    #pragma unroll
    for (int u = 0; u < 12; ++u) o[u] = make_float4(0.f, 0.f, 0.f, 0.f);
    float m_i = -INFINITY, l_i = 0.f;

    for (int j0 = 0; j0 < N_; j0 += 16) {
        __syncthreads();   // previous tile's Xs reads complete
        // stage 16 x 768 floats: 12 float4 per thread, fully coalesced
        #pragma unroll
        for (int u = 0; u < 12; ++u) {
            int idx = t + 256 * u;            // float4 index 0..3071
            int jr  = idx / 192;              // row in tile
            int c4  = idx - jr * 192;         // float4 col
            *(float4*)&Xs[idx * 4] =
                *(const float4*)&xb[(size_t)(j0 + jr) * H_ + c4 * 4];
        }
        __syncthreads();

        // ---- scores for this j-tile ----
        float s[16];
        #pragma unroll
        for (int j = 0; j < 16; ++j) {
            const float* xr = &Xs[j * H_];
            float p = 0.f;
            #pragma unroll
            for (int u = 0; u < 12; ++u) {
                float4 xv = *(const float4*)&xr[hq * 4 + 64 * u];
                p += q[u].x * xv.x + q[u].y * xv.y + q[u].z * xv.z + q[u].w * xv.w;
            }
            // reduce the 16 h-stripes (lanes sharing il)
            p += __shfl_xor(p, 1, 16);
            p += __shfl_xor(p, 2, 16);
            p += __shfl_xor(p, 4, 16);
            p += __shfl_xor(p, 8, 16);
            p += bias;
            if (gi == j0 + j) p = 0.f;   // reference zeroes the diagonal AFTER bias
            s[j] = p;
        }

        // ---- online softmax update ----
        float mt = m_i;
        #pragma unroll
        for (int j = 0; j < 16; ++j) mt = fmaxf(mt, s[j]);
        float alpha = __expf(m_i - mt);
        m_i = mt;
        float psum = 0.f;
        #pragma unroll
        for (int j = 0; j < 16; ++j) {
            s[j] = __expf(s[j] - mt);
            psum += s[j];
        }
        l_i = l_i * alpha + psum;
        #pragma unroll
        for (int u = 0; u < 12; ++u) {
            o[u].x *= alpha; o[u].y *= alpha; o[u].z *= alpha; o[u].w *= alpha;
        }

        // ---- PV accumulate ----
        #pragma unroll
        for (int j = 0; j < 16; ++j) {
            const float p = s[j];
            const float* xr = &Xs[j * H_];
            #pragma unroll
            for (int u = 0; u < 12; ++u) {
                float4 xv = *(const float4*)&xr[hq * 4 + 64 * u];
                o[u].x += p * xv.x; o[u].y += p * xv.y;
                o[u].z += p * xv.z; o[u].w += p * xv.w;
            }
        }
    }

    const float inv = 1.f / l_i;
    #pragma unroll
    for (int u = 0; u < 12; ++u) {
        float4 v = make_float4(o[u].x * inv, o[u].y * inv, o[u].z * inv, o[u].w * inv);
        *(float4*)&orow[hq * 4 + 64 * u] = v;
    }
}

extern "C" void kernel_launch(void* const* d_in, const int* in_sizes, int n_in,
                              void* d_out, int out_size, void* d_ws, size_t ws_size,
                              hipStream_t stream) {
    const float* x    = (const float*)d_in[0];   // [B,N,H]
    const float* W    = (const float*)d_in[1];   // [H,H]
    const float* bias = (const float*)d_in[2];   // [1]
    float* out = (float*)d_out;                  // [B,N,H]; also used as xW scratch

    // Kernel 1: out <- x @ W
    gemm_xw<<<dim3(H_ / 64, (B_ * N_) / 64), 256, 0, stream>>>(x, W, out);
    // Kernel 2: out rows <- softmax(xW . x^T, diag=0) @ x   (reads own rows as Q first)
    attn<<<dim3(N_ / 16, B_), 256, 0, stream>>>(x, bias, out);
}

// Round 2
// 1020.047 us; speedup vs baseline: 5.9552x; 5.9552x over previous
//
#include <hip/hip_runtime.h>
#include <hip/hip_bf16.h>
#include <math.h>

// Problem constants: B=64, N=512, H=768. fp32 in/out.
static constexpr int B_ = 64;
static constexpr int N_ = 512;
static constexpr int H_ = 768;

typedef float f32x16 __attribute__((ext_vector_type(16)));
typedef short bf16x8 __attribute__((ext_vector_type(8)));

static __device__ __forceinline__ f32x16 mfma32(bf16x8 a, bf16x8 b, f32x16 c) {
    return __builtin_amdgcn_mfma_f32_32x32x16_bf16(a, b, c, 0, 0, 0);
}

// hi/lo bf16 split via truncation. hi = trunc16(x); lo = trunc16(x - hi_f32).
// x - hi is exact (Sterbenz); total reconstruction err ~ |x| * 2^-16.
static __device__ __forceinline__ uint32_t pack_hi2(float f0, float f1) {
    uint32_t u0 = __float_as_uint(f0), u1 = __float_as_uint(f1);
    return (u1 & 0xFFFF0000u) | (u0 >> 16);
}
static __device__ __forceinline__ uint32_t pack_lo2(float f0, float f1) {
    uint32_t u0 = __float_as_uint(f0), u1 = __float_as_uint(f1);
    float l0 = f0 - __uint_as_float(u0 & 0xFFFF0000u);
    float l1 = f1 - __uint_as_float(u1 & 0xFFFF0000u);
    uint32_t v0 = __float_as_uint(l0), v1 = __float_as_uint(l1);
    return (v1 & 0xFFFF0000u) | (v0 >> 16);
}

// C/D 32x32 frag row for reg, half=lane>>5 (m74/m101-verified layout)
#define R32(reg, half) (((reg) & 3) + 8 * ((reg) >> 2) + 4 * (half))

// ---------------------------------------------------------------------------
// Kernel 1: Q = X @ W (fp32 VALU, 64x64 tile). Epilogue writes Q into d_out in
// grouped-split format: per row, 96 groups of [16B hi-bf16 x8 | 16B lo-bf16 x8]
// = 3072B/row (same footprint as fp32 row). In-place safe for kernel 3.
// ---------------------------------------------------------------------------
__global__ __launch_bounds__(256) void gemm_xw(const float* __restrict__ X,
                                               const float* __restrict__ W,
                                               uint32_t* __restrict__ C) {
    __shared__ float As[16][68];
    __shared__ float Ws[16][68];

    const int t  = threadIdx.x;
    const int m0 = blockIdx.y * 64;
    const int n0 = blockIdx.x * 64;
    const int tx = t & 15, ty = t >> 4;
    const int tm = ty * 4, tn = tx * 4;

    const int ar  = t >> 2;
    const int ac4 = (t & 3) * 4;
    const int wr  = t >> 4;
    const int wc4 = (t & 15) * 4;

    float acc[4][4] = {};

    for (int k0 = 0; k0 < H_; k0 += 16) {
        float4 av = *(const float4*)&X[(size_t)(m0 + ar) * H_ + k0 + ac4];
        float4 wv = *(const float4*)&W[(size_t)(k0 + wr) * H_ + n0 + wc4];
        __syncthreads();
        As[ac4 + 0][ar] = av.x;
        As[ac4 + 1][ar] = av.y;
        As[ac4 + 2][ar] = av.z;
        As[ac4 + 3][ar] = av.w;
        *(float4*)&Ws[wr][wc4] = wv;
        __syncthreads();
        #pragma unroll
        for (int k = 0; k < 16; ++k) {
            float4 a4 = *(const float4*)&As[k][tm];
            float4 b4 = *(const float4*)&Ws[k][tn];
            acc[0][0] += a4.x * b4.x; acc[0][1] += a4.x * b4.y; acc[0][2] += a4.x * b4.z; acc[0][3] += a4.x * b4.w;
            acc[1][0] += a4.y * b4.x; acc[1][1] += a4.y * b4.y; acc[1][2] += a4.y * b4.z; acc[1][3] += a4.y * b4.w;
            acc[2][0] += a4.z * b4.x; acc[2][1] += a4.z * b4.y; acc[2][2] += a4.z * b4.z; acc[2][3] += a4.z * b4.w;
            acc[3][0] += a4.w * b4.x; acc[3][1] += a4.w * b4.y; acc[3][2] += a4.w * b4.z; acc[3][3] += a4.w * b4.w;
        }
    }

    const int c0   = n0 + tn;          // global col of this thread's 4 cols
    const int g    = c0 >> 3;          // 8-col group
    const int half = (c0 >> 2) & 1;    // which half of the group
    #pragma unroll
    for (int r = 0; r < 4; ++r) {
        uint32_t hi0 = pack_hi2(acc[r][0], acc[r][1]);
        uint32_t hi1 = pack_hi2(acc[r][2], acc[r][3]);
        uint32_t lo0 = pack_lo2(acc[r][0], acc[r][1]);
        uint32_t lo1 = pack_lo2(acc[r][2], acc[r][3]);
        uint32_t* orow = C + (size_t)(m0 + tm + r) * H_;  // 768 u32 per row
        *(uint2*)&orow[g * 8 + half * 2]     = make_uint2(hi0, hi1);
        *(uint2*)&orow[g * 8 + 4 + half * 2] = make_uint2(lo0, lo1);
    }
}

// ---------------------------------------------------------------------------
// Kernel 2: scores + softmax -> normalized P (bf16) in ws.
// Block = 64 i-rows (grid 8 x 64), 4 waves. 3-pass hi/lo split MFMA 32x32x16.
// j staged 128 rows x 96-k chunks (hi+lo bf16, padded stride 104).
// Wave w owns j columns {jb*128 + w*32 + (0..31)}. Per-wave softmax partials
// combined across waves via small LDS arrays; P normalized before store.
// ---------------------------------------------------------------------------
__global__ __launch_bounds__(256, 2) void attn_scores(const float* __restrict__ X,
                                                      const uint32_t* __restrict__ Q32,
                                                      const float* __restrict__ bias_p,
                                                      __hip_bfloat16* __restrict__ P) {
    __shared__ __align__(16) unsigned short Khi[128][104];
    __shared__ __align__(16) unsigned short Klo[128][104];
    __shared__ float smax[4][64];
    __shared__ float ssum[4][64];
    __shared__ float sscale[4][64];

    const int t    = threadIdx.x;
    const int w    = t >> 6;
    const int lane = t & 63;
    const int half = lane >> 5;
    const int ln   = lane & 31;
    const int b    = blockIdx.y;
    const int I0   = blockIdx.x * 64;
    const float bias = bias_p[0];

    const float* xb = X + (size_t)b * N_ * H_;

    f32x16 acc[2][4];
    f32x16 zf = {};
    #pragma unroll
    for (int is = 0; is < 2; ++is)
        #pragma unroll
        for (int jb = 0; jb < 4; ++jb) acc[is][jb] = zf;

    for (int jb = 0; jb < 4; ++jb) {
        for (int kph = 0; kph < 8; ++kph) {
            __syncthreads();
            // stage 128 j-rows x 96 k (hi+lo) from fp32 global
            #pragma unroll
            for (int u = 0; u < 12; ++u) {
                int idx = t + 256 * u;
                int r   = idx / 24;
                int c4  = idx - r * 24;
                float4 f = *(const float4*)&xb[(size_t)(jb * 128 + r) * H_ + kph * 96 + c4 * 4];
                uint32_t h0 = pack_hi2(f.x, f.y), h1 = pack_hi2(f.z, f.w);
                uint32_t l0 = pack_lo2(f.x, f.y), l1 = pack_lo2(f.z, f.w);
                *(uint2*)&Khi[r][c4 * 4] = make_uint2(h0, h1);
                *(uint2*)&Klo[r][c4 * 4] = make_uint2(l0, l1);
            }
            __syncthreads();
            #pragma unroll
            for (int ks = 0; ks < 6; ++ks) {
                // Q A-frags from grouped-split global (L1-resident within kph)
                const int kgrp = kph * 12 + ks * 2 + half;
                bf16x8 qh[2], ql[2];
                #pragma unroll
                for (int is = 0; is < 2; ++is) {
                    const uint32_t* qr =
                        Q32 + ((size_t)b * N_ + I0 + is * 32 + ln) * H_ + (size_t)kgrp * 8;
                    qh[is] = *(const bf16x8*)(qr);
                    ql[is] = *(const bf16x8*)(qr + 4);
                }
                // K B-frags from LDS
                const int koff = ks * 16 + half * 8;
                bf16x8 kh = *(const bf16x8*)&Khi[w * 32 + ln][koff];
                bf16x8 kl = *(const bf16x8*)&Klo[w * 32 + ln][koff];
                #pragma unroll
                for (int is = 0; is < 2; ++is) {
                    acc[is][jb] = mfma32(qh[is], kh, acc[is][jb]);
                    acc[is][jb] = mfma32(qh[is], kl, acc[is][jb]);
                    acc[is][jb] = mfma32(ql[is], kh, acc[is][jb]);
                }
            }
        }
    }

    // bias + diagonal zero (ref zeroes scores at i==j AFTER bias, pre-softmax)
    const int gj = /* this lane's global j col per jb: */ w * 32 + ln;  // + jb*128
    #pragma unroll
    for (int is = 0; is < 2; ++is)
        #pragma unroll
        for (int jb = 0; jb < 4; ++jb)
            #pragma unroll
            for (int reg = 0; reg < 16; ++reg) {
                float v = acc[is][jb][reg] + bias;
                int gi = I0 + is * 32 + R32(reg, half);
                if (gi == jb * 128 + gj) v = 0.0f;
                acc[is][jb][reg] = v;
            }

    // wave-local row max over this wave's 128 j
    float mrow[2][16];
    #pragma unroll
    for (int is = 0; is < 2; ++is)
        #pragma unroll
        for (int reg = 0; reg < 16; ++reg) {
            float m = acc[is][0][reg];
            #pragma unroll
            for (int jb = 1; jb < 4; ++jb) m = fmaxf(m, acc[is][jb][reg]);
            #pragma unroll
            for (int d = 1; d < 32; d <<= 1) m = fmaxf(m, __shfl_xor(m, d));
            mrow[is][reg] = m;
            if (ln == 0) smax[w][is * 32 + R32(reg, half)] = m;
        }

    // exp + wave-local row sum
    #pragma unroll
    for (int is = 0; is < 2; ++is)
        #pragma unroll
        for (int reg = 0; reg < 16; ++reg) {
            float s = 0.f;
            #pragma unroll
            for (int jb = 0; jb < 4; ++jb) {
                float e = __expf(acc[is][jb][reg] - mrow[is][reg]);
                acc[is][jb][reg] = e;
                s += e;
            }
            #pragma unroll
            for (int d = 1; d < 32; d <<= 1) s += __shfl_xor(s, d);
            if (ln == 0) ssum[w][is * 32 + R32(reg, half)] = s;
        }
    __syncthreads();

    // combine across the 4 waves; sscale[w][row] = exp(m_w - M) / L
    if (t < 64) {
        float M = smax[0][t];
        #pragma unroll
        for (int w2 = 1; w2 < 4; ++w2) M = fmaxf(M, smax[w2][t]);
        float L = 0.f;
        #pragma unroll
        for (int w2 = 0; w2 < 4; ++w2) L += ssum[w2][t] * __expf(smax[w2][t] - M);
        float invL = 1.0f / L;
        #pragma unroll
        for (int w2 = 0; w2 < 4; ++w2) sscale[w2][t] = __expf(smax[w2][t] - M) * invL;
    }
    __syncthreads();

    // store normalized P (bf16) to ws
    __hip_bfloat16* Pb = P + (size_t)b * N_ * N_;
    #pragma unroll
    for (int is = 0; is < 2; ++is)
        #pragma unroll
        for (int reg = 0; reg < 16; ++reg) {
            int row = is * 32 + R32(reg, half);
            float sc = sscale[w][row];
            #pragma unroll
            for (int jb = 0; jb < 4; ++jb) {
                float p = acc[is][jb][reg] * sc;
                Pb[(size_t)(I0 + row) * N_ + jb * 128 + w * 32 + ln] = __float2bfloat16(p);
            }
        }
}

// ---------------------------------------------------------------------------
// Kernel 3: O = P (bf16) @ X (bf16 RNE), MFMA 32x32x16. Block tile 128i x 256h,
// wave tile 64i x 128h (2x4 frags -> 42 flop/LDS-byte, compute-bound).
// X tile transposed into LDS (h-major, stride 40 bf16 -> bank-scrambled).
// ---------------------------------------------------------------------------
__global__ __launch_bounds__(256, 2) void pv_gemm(const float* __restrict__ X,
                                                  const __hip_bfloat16* __restrict__ P,
                                                  float* __restrict__ O) {
    __shared__ __align__(16) unsigned short Pt[128][40];
    __shared__ __align__(16) unsigned short Vt[256][40];

    const int t    = threadIdx.x;
    const int w    = t >> 6;
    const int lane = t & 63;
    const int half = lane >> 5;
    const int ln   = lane & 31;
    const int wi   = w & 1;
    const int wh   = w >> 1;
    const int b    = blockIdx.z;
    const int I0   = blockIdx.y * 128;
    const int H0   = blockIdx.x * 256;

    const unsigned short* Pb = (const unsigned short*)P + (size_t)b * N_ * N_;
    const float* xb = X + (size_t)b * N_ * H_;

    f32x16 acc[2][4];
    f32x16 zf = {};
    #pragma unroll
    for (int is = 0; is < 2; ++is)
        #pragma unroll
        for (int hs = 0; hs < 4; ++hs) acc[is][hs] = zf;

    for (int j0 = 0; j0 < N_; j0 += 32) {
        __syncthreads();
        // stage P tile 128 x 32 (row-major, already bf16)
        #pragma unroll
        for (int u = 0; u < 2; ++u) {
            int idx = t + 256 * u;
            int r   = idx >> 2;
            int c8  = idx & 3;
            uint4 v = *(const uint4*)&Pb[(size_t)(I0 + r) * N_ + j0 + c8 * 8];
            *(uint4*)&Pt[r][c8 * 8] = v;
        }
        // stage V tile transposed: thread t owns h-col H0+t, walks 32 j-rows
        {
            const float* xc = xb + (size_t)j0 * H_ + H0 + t;
            #pragma unroll
            for (int jj = 0; jj < 32; jj += 2) {
                float f0 = xc[(size_t)jj * H_];
                float f1 = xc[(size_t)(jj + 1) * H_];
                __hip_bfloat16 b0 = __float2bfloat16(f0);
                __hip_bfloat16 b1 = __float2bfloat16(f1);
                unsigned short u0, u1;
                __builtin_memcpy(&u0, &b0, 2);
                __builtin_memcpy(&u1, &b1, 2);
                *(uint32_t*)&Vt[t][jj] = ((uint32_t)u1 << 16) | u0;
            }
        }
        __syncthreads();
        #pragma unroll
        for (int ks = 0; ks < 2; ++ks) {
            const int koff = ks * 16 + half * 8;
            bf16x8 a[2], v[4];
            #pragma unroll
            for (int is = 0; is < 2; ++is)
                a[is] = *(const bf16x8*)&Pt[wi * 64 + is * 32 + ln][koff];
            #pragma unroll
            for (int hs = 0; hs < 4; ++hs)
                v[hs] = *(const bf16x8*)&Vt[wh * 128 + hs * 32 + ln][koff];
            #pragma unroll
            for (int is = 0; is < 2; ++is)
                #pragma unroll
                for (int hs = 0; hs < 4; ++hs)
                    acc[is][hs] = mfma32(a[is], v[hs], acc[is][hs]);
        }
    }

    float* Ob = O + (size_t)b * N_ * H_;
    #pragma unroll
    for (int is = 0; is < 2; ++is)
        #pragma unroll
        for (int hs = 0; hs < 4; ++hs)
            #pragma unroll
            for (int reg = 0; reg < 16; ++reg) {
                int row = I0 + wi * 64 + is * 32 + R32(reg, half);
                int col = H0 + wh * 128 + hs * 32 + ln;
                Ob[(size_t)row * H_ + col] = acc[is][hs][reg];
            }
}

extern "C" void kernel_launch(void* const* d_in, const int* in_sizes, int n_in,
                              void* d_out, int out_size, void* d_ws, size_t ws_size,
                              hipStream_t stream) {
    const float* x    = (const float*)d_in[0];   // [B,N,H]
    const float* W    = (const float*)d_in[1];   // [H,H]
    const float* bias = (const float*)d_in[2];   // [1]

    // K1: d_out <- split(X @ W)  (grouped bf16 hi/lo, same footprint as fp32)
    gemm_xw<<<dim3(H_ / 64, (B_ * N_) / 64), 256, 0, stream>>>(
        x, W, (uint32_t*)d_out);
    // K2: ws <- normalized softmax(Q . X^T + bias, diag->0)  as bf16 [B,N,N]
    attn_scores<<<dim3(N_ / 64, B_), 256, 0, stream>>>(
        x, (const uint32_t*)d_out, bias, (__hip_bfloat16*)d_ws);
    // K3: d_out <- P @ X  (fp32 result)
    pv_gemm<<<dim3(H_ / 256, N_ / 128, B_), 256, 0, stream>>>(
        x, (const __hip_bfloat16*)d_ws, (float*)d_out);
}